// Round 3
// baseline (635.054 us; speedup 1.0000x reference)
//
#include <hip/hip_runtime.h>

// Problem constants (MeshConv: B=8, M=40000, FIN=64, K=6, FOUT=64, NNZ=320000)
#define Mn    40000
#define Bn    8
#define FINn  64
#define Kn    6
#define FOUTn 64
#define NNZn  320000
#define Cn    512   // FIN*B values per Chebyshev level per row
#define NB    ((Mn + 255) / 256)   // scan blocks = 157

// Level layout (fp16): xh[lev][b][m][f]  -- f contiguous (64 halves = 128B/row),
// so the GEMM reads one contiguous 8KB block per (level, b, 64-row m-tile).

typedef _Float16 half8 __attribute__((ext_vector_type(8)));  // MFMA A/B frag
typedef __attribute__((ext_vector_type(4))) float floatx4;   // MFMA accumulator

__device__ __forceinline__ ushort f2h(float f) {
    _Float16 h = (_Float16)f;
    return *(ushort*)&h;
}

// ---------------- CSR build ----------------

__global__ __launch_bounds__(256) void k_hist(const int* __restrict__ rows,
                                              int* __restrict__ cnt) {
    int e = blockIdx.x * 256 + threadIdx.x;
    if (e < NNZn) atomicAdd(&cnt[rows[e]], 1);
}

// hierarchical scan, phase 1: per-block local exclusive scan + block sums
__global__ __launch_bounds__(256) void k_scan_part(const int* __restrict__ cnt,
                                                   int* __restrict__ rowptr,
                                                   int* __restrict__ bsum) {
    __shared__ int part[256];
    int tid = threadIdx.x;
    int r = blockIdx.x * 256 + tid;
    int v = (r < Mn) ? cnt[r] : 0;
    part[tid] = v;
    __syncthreads();
    for (int off = 1; off < 256; off <<= 1) {
        int t = (tid >= off) ? part[tid - off] : 0;
        __syncthreads();
        part[tid] += t;
        __syncthreads();
    }
    if (r < Mn) rowptr[r] = part[tid] - v;     // block-local exclusive prefix
    if (tid == 255) bsum[blockIdx.x] = part[255];
}

// phase 2: single-block scan of the NB block sums
__global__ __launch_bounds__(256) void k_scan_bsums(const int* __restrict__ bsum,
                                                    int* __restrict__ boff,
                                                    int* __restrict__ rowptr) {
    __shared__ int part[256];
    int tid = threadIdx.x;
    int v = (tid < NB) ? bsum[tid] : 0;
    part[tid] = v;
    __syncthreads();
    for (int off = 1; off < 256; off <<= 1) {
        int t = (tid >= off) ? part[tid - off] : 0;
        __syncthreads();
        part[tid] += t;
        __syncthreads();
    }
    if (tid < NB) boff[tid] = part[tid] - v;
    if (tid == 255) rowptr[Mn] = part[255];    // grand total
}

// phase 3: add block offsets; also emit the scatter write-cursor copy
__global__ __launch_bounds__(256) void k_scan_add(int* __restrict__ rowptr,
                                                  const int* __restrict__ boff,
                                                  int* __restrict__ wcur) {
    int r = blockIdx.x * 256 + threadIdx.x;
    if (r < Mn) {
        int v = rowptr[r] + boff[blockIdx.x];
        rowptr[r] = v;
        wcur[r] = v;
    }
}

__global__ __launch_bounds__(256) void k_scatter(const int* __restrict__ rows,
                                                 const int* __restrict__ cols,
                                                 const float* __restrict__ vals,
                                                 int* __restrict__ wcur,
                                                 int2* __restrict__ csr) {
    int e = blockIdx.x * 256 + threadIdx.x;
    if (e < NNZn) {
        int p = atomicAdd(&wcur[rows[e]], 1);
        int2 cv; cv.x = cols[e]; cv.y = __float_as_int(vals[e]);
        csr[p] = cv;
    }
}

// ---------------- x -> x0 (fp16): pure streaming convert ----------------
// x is [B][M][F] fp32, level-0 slot is [b][m][f] fp16 -> identical ordering.

__global__ __launch_bounds__(256) void k_transpose_h(const float* __restrict__ x,
                                                     ushort* __restrict__ x0h) {
    size_t i = ((size_t)blockIdx.x * 256 + threadIdx.x) * 8;   // half index
    float4 a = *(const float4*)(x + i);
    float4 b = *(const float4*)(x + i + 4);
    union { uint4 u; ushort h[8]; } s;
    s.h[0] = f2h(a.x); s.h[1] = f2h(a.y); s.h[2] = f2h(a.z); s.h[3] = f2h(a.w);
    s.h[4] = f2h(b.x); s.h[5] = f2h(b.y); s.h[6] = f2h(b.z); s.h[7] = f2h(b.w);
    *(uint4*)(x0h + i) = s.u;
}

// ---------------- SpMM (all-fp16 state) + Chebyshev recurrence ----------------
// acc = -xc[m] + sum val * xc[col] (fp32 arithmetic, fp16 storage);
// xn = first ? acc : 2*acc - xp.  One row per wave: lane l covers b = l>>3,
// f = (l&7)*8 .. +8  (8 chunks of 128B at Mn*128B stride).
// Edge loop unrolled 8-deep; xp read issued BEFORE the loop (overlaps gathers).

__device__ __forceinline__ void fmah8(float* a, uint4 g, float w) {
    union { uint4 u; _Float16 h[8]; } c; c.u = g;
#pragma unroll
    for (int i = 0; i < 8; ++i) a[i] += w * (float)c.h[i];
}

__global__ __launch_bounds__(256) void k_spmm_h(const ushort* __restrict__ xc,
                                                const ushort* __restrict__ xp,
                                                ushort* __restrict__ xn,
                                                const int* __restrict__ rowptr,
                                                const int2* __restrict__ csr,
                                                int first) {
    int t = threadIdx.x;
    int lane = t & 63;
    int m = blockIdx.x * 4 + (t >> 6);
    const uint4* xc4 = (const uint4*)xc;
    // per-lane constant offset in uint4 units: b*(Mn*8) + part
    size_t loff = (size_t)(lane >> 3) * ((size_t)Mn * 8) + (lane & 7);
    uint4 v = xc4[loff + (size_t)m * 8];
    uint4 p;
    if (!first) p = ((const uint4*)xp)[loff + (size_t)m * 8];   // early issue
    float a[8];
    { union { uint4 u; _Float16 h[8]; } c; c.u = v;
#pragma unroll
      for (int i = 0; i < 8; ++i) a[i] = -(float)c.h[i]; }

    int e = rowptr[m], end = rowptr[m + 1];
    for (; e + 8 <= end; e += 8) {
        int2 cv[8];
#pragma unroll
        for (int i = 0; i < 8; ++i) cv[i] = csr[e + i];
        uint4 g[8];
#pragma unroll
        for (int i = 0; i < 8; ++i) g[i] = xc4[loff + (size_t)cv[i].x * 8];
#pragma unroll
        for (int i = 0; i < 8; ++i) fmah8(a, g[i], __int_as_float(cv[i].y));
    }
    for (; e + 4 <= end; e += 4) {
        int2 cv0 = csr[e],     cv1 = csr[e + 1];
        int2 cv2 = csr[e + 2], cv3 = csr[e + 3];
        uint4 g0 = xc4[loff + (size_t)cv0.x * 8];
        uint4 g1 = xc4[loff + (size_t)cv1.x * 8];
        uint4 g2 = xc4[loff + (size_t)cv2.x * 8];
        uint4 g3 = xc4[loff + (size_t)cv3.x * 8];
        fmah8(a, g0, __int_as_float(cv0.y));
        fmah8(a, g1, __int_as_float(cv1.y));
        fmah8(a, g2, __int_as_float(cv2.y));
        fmah8(a, g3, __int_as_float(cv3.y));
    }
    for (; e < end; ++e) {
        int2 cv = csr[e];
        uint4 g = xc4[loff + (size_t)cv.x * 8];
        fmah8(a, g, __int_as_float(cv.y));
    }

    if (!first) {
        union { uint4 u; _Float16 h[8]; } c; c.u = p;
#pragma unroll
        for (int i = 0; i < 8; ++i) a[i] = 2.f * a[i] - (float)c.h[i];
    }
    union { uint4 u; _Float16 h[8]; } s;
#pragma unroll
    for (int i = 0; i < 8; ++i) s.h[i] = (_Float16)a[i];
    ((uint4*)xn)[loff + (size_t)m * 8] = s.u;
}

// ---------------- W -> MFMA B-fragment pre-swizzle (fp16) ----------------
// Wfrag[((kk*4 + n)*64 + lane)*8 + j] = f16( W[(f*6+lev)*64 + fo] )
//   kk = global K-chunk (0..11), lev = kk>>1, f = (kk&1)*32 + (lane>>4)*8 + j,
//   fo = n*16 + (lane&15)

__global__ __launch_bounds__(256) void k_wfrag(const float* __restrict__ W,
                                               ushort* __restrict__ wfrag) {
    int idx = blockIdx.x * 256 + threadIdx.x;   // 12*4*64*8 = 24576
    if (idx >= 12 * 4 * 64 * 8) return;
    int j    = idx & 7;
    int lane = (idx >> 3) & 63;
    int n    = (idx >> 9) & 3;
    int kk   = idx >> 11;
    int k    = (lane >> 4) * 8 + j;
    int lev  = kk >> 1;
    int f    = (kk & 1) * 32 + k;
    int fo   = n * 16 + (lane & 15);
    wfrag[idx] = f2h(W[(f * Kn + lev) * FOUTn + fo]);
}

// ---------------- MFMA projection GEMM (fp16 inputs, fp32 acc) ----------------
// out[b, m, fo] = sum over all 6 levels, f:
//   X[lev][b][m][f] * W[(f*6+lev)*64+fo]
// Block: 256 thr (4 waves), tile 64 m x 64 fo, one b per block; single pass
// over all 6 levels. ALL 6 levels' staging loads (12 x dwordx4 per thread)
// are issued up front -> one latency exposure per block instead of six.

__global__ __launch_bounds__(256) void k_gemm_mfma(const ushort* __restrict__ xh,
                                                   const ushort* __restrict__ wfrag,
                                                   float* __restrict__ out) {
    __shared__ __align__(16) ushort As[64 * 64];   // 8KB, XOR-swizzled content
    int t    = threadIdx.x;
    int wv   = t >> 6;
    int lane = t & 63;
    int q    = lane >> 4, r = lane & 15;
    int b    = blockIdx.x & 7;
    int m0   = (blockIdx.x >> 3) * 64;

    // staging: 512 x 16B chunks; thread t owns chunks e = t and e = t+256.
    // chunk e -> srow = e>>3, spart = e&7; global read is LINEAR, LDS dest is
    // swizzled: byte = srow*128 + (spart*16 ^ ((srow&7)<<4)).
    int srow0 = t >> 3, spart = t & 7;
    int srow1 = srow0 + 32;
    const size_t lstride4 = (size_t)Bn * Mn * 8;         // level stride, uint4 units
    size_t gbase4 = (((size_t)b * Mn + m0) * 64) / 8;    // uint4 units
    const uint4* xh4 = (const uint4*)xh;
    const uint4* src0 = xh4 + gbase4 + (size_t)srow0 * 8 + spart;
    const uint4* src1 = xh4 + gbase4 + (size_t)srow1 * 8 + spart;
    int d0 = srow0 * 128 + ((spart * 16) ^ ((srow0 & 7) << 4));
    int d1 = srow1 * 128 + ((spart * 16) ^ ((srow1 & 7) << 4));

    int row  = wv * 16 + r;        // A-fragment row this lane reads
    int asw  = row & 7;            // read-side swizzle
    int abase = row * 64;          // halves

    floatx4 acc[4];
    acc[0] = (floatx4)0.f; acc[1] = (floatx4)0.f;
    acc[2] = (floatx4)0.f; acc[3] = (floatx4)0.f;

    // prefetch ALL 6 levels (fully static indexing -> stays in VGPRs)
    uint4 va[6], vb[6];
#pragma unroll
    for (int lev = 0; lev < 6; ++lev) {
        va[lev] = src0[(size_t)lev * lstride4];
        vb[lev] = src1[(size_t)lev * lstride4];
    }

#pragma unroll
    for (int lev = 0; lev < 6; ++lev) {
        __syncthreads();                       // prior level's LDS reads done
        *(uint4*)((char*)As + d0) = va[lev];
        *(uint4*)((char*)As + d1) = vb[lev];
        __syncthreads();                       // staging visible
#pragma unroll
        for (int half = 0; half < 2; ++half) {
            half8 af = *(const half8*)&As[abase + ((((half * 4) + q) ^ asw) << 3)];
            int kkg = lev * 2 + half;
            const ushort* wf = wfrag + ((size_t)(kkg * 4) * 64 + lane) * 8;
            acc[0] = __builtin_amdgcn_mfma_f32_16x16x32_f16(af, *(const half8*)(wf),        acc[0], 0, 0, 0);
            acc[1] = __builtin_amdgcn_mfma_f32_16x16x32_f16(af, *(const half8*)(wf + 512),  acc[1], 0, 0, 0);
            acc[2] = __builtin_amdgcn_mfma_f32_16x16x32_f16(af, *(const half8*)(wf + 1024), acc[2], 0, 0, 0);
            acc[3] = __builtin_amdgcn_mfma_f32_16x16x32_f16(af, *(const half8*)(wf + 1536), acc[3], 0, 0, 0);
        }
    }

    // C/D layout: col = lane&15, row = (lane>>4)*4 + reg
    size_t obase = ((size_t)b * Mn + m0 + wv * 16) * FOUTn;
#pragma unroll
    for (int n = 0; n < 4; ++n) {
#pragma unroll
        for (int reg = 0; reg < 4; ++reg) {
            int orow = q * 4 + reg;
            out[obase + (size_t)orow * FOUTn + n * 16 + r] = acc[n][reg];
        }
    }
}

// ---------------- fallback fp32 kernels (ws too small; not expected) ----------------

__global__ __launch_bounds__(512) void k_transpose_f(const float* __restrict__ x,
                                                     float* __restrict__ x0) {
    int m = blockIdx.x, t = threadIdx.x;
    int b = t >> 6, f = t & 63;
    x0[(size_t)m * Cn + t] = x[((size_t)b * Mn + m) * 64 + f];
}

__global__ __launch_bounds__(256) void k_spmm_f32(const float4* __restrict__ xc,
                                                  const float4* __restrict__ xp,
                                                  float4* __restrict__ xn,
                                                  const int* __restrict__ rowptr,
                                                  const int2* __restrict__ csr,
                                                  int first) {
    int t = threadIdx.x;
    int lane = t & 63;
    int m = blockIdx.x * 4 + (t >> 6);
    size_t rb = (size_t)m * 128;
    float4 v0 = xc[rb + lane];
    float4 v1 = xc[rb + 64 + lane];
    float4 a0 = make_float4(-v0.x, -v0.y, -v0.z, -v0.w);
    float4 a1 = make_float4(-v1.x, -v1.y, -v1.z, -v1.w);
    int e = rowptr[m], end = rowptr[m + 1];
    for (; e < end; ++e) {
        int2 cv = csr[e];
        float w = __int_as_float(cv.y);
        const float4* r = xc + (size_t)cv.x * 128;
        float4 g0 = r[lane], g1 = r[64 + lane];
        a0.x += w * g0.x; a0.y += w * g0.y; a0.z += w * g0.z; a0.w += w * g0.w;
        a1.x += w * g1.x; a1.y += w * g1.y; a1.z += w * g1.z; a1.w += w * g1.w;
    }
    if (!first) {
        float4 p0 = xp[rb + lane];
        float4 p1 = xp[rb + 64 + lane];
        a0.x = 2.f * a0.x - p0.x; a0.y = 2.f * a0.y - p0.y;
        a0.z = 2.f * a0.z - p0.z; a0.w = 2.f * a0.w - p0.w;
        a1.x = 2.f * a1.x - p1.x; a1.y = 2.f * a1.y - p1.y;
        a1.z = 2.f * a1.z - p1.z; a1.w = 2.f * a1.w - p1.w;
    }
    xn[rb + lane] = a0;
    xn[rb + 64 + lane] = a1;
}

__global__ __launch_bounds__(256) void k_gemm2(const float* __restrict__ xa,
                                               const float* __restrict__ xb,
                                               const float* __restrict__ W,
                                               float* __restrict__ out,
                                               int ka, int kb, int accum) {
    __shared__ __align__(16) float Wa[64 * 64];
    __shared__ __align__(16) float Wb[64 * 64];
    __shared__ __align__(16) float xsa[4 * Cn];
    __shared__ __align__(16) float xsb[4 * Cn];
    int t = threadIdx.x;
    size_t m0 = (size_t)blockIdx.x * 4;
    for (int i = t; i < 4096; i += 256) {
        int f = i >> 6, fo = i & 63;
        Wa[i] = W[(f * Kn + ka) * FOUTn + fo];
        Wb[i] = W[(f * Kn + kb) * FOUTn + fo];
    }
    for (int i = t; i < 4 * Cn; i += 256) {
        xsa[i] = xa[m0 * Cn + i];
        xsb[i] = xb[m0 * Cn + i];
    }
    __syncthreads();
    int fo  = (t & 15) * 4;
    int idx = t >> 4;
    int m   = idx & 3;
    int bq  = idx >> 2;
    float4 acc0 = make_float4(0.f, 0.f, 0.f, 0.f);
    float4 acc1 = make_float4(0.f, 0.f, 0.f, 0.f);
    for (int f = 0; f < 64; ++f) {
        float4 wa = *(const float4*)&Wa[f * 64 + fo];
        float a0 = xsa[m * Cn + bq * 64 + f];
        float a1 = xsa[m * Cn + (bq + 4) * 64 + f];
        acc0.x += a0 * wa.x; acc0.y += a0 * wa.y; acc0.z += a0 * wa.z; acc0.w += a0 * wa.w;
        acc1.x += a1 * wa.x; acc1.y += a1 * wa.y; acc1.z += a1 * wa.z; acc1.w += a1 * wa.w;
        float4 wb = *(const float4*)&Wb[f * 64 + fo];
        float b0 = xsb[m * Cn + bq * 64 + f];
        float b1 = xsb[m * Cn + (bq + 4) * 64 + f];
        acc0.x += b0 * wb.x; acc0.y += b0 * wb.y; acc0.z += b0 * wb.z; acc0.w += b0 * wb.w;
        acc1.x += b1 * wb.x; acc1.y += b1 * wb.y; acc1.z += b1 * wb.z; acc1.w += b1 * wb.w;
    }
    size_t o0 = (((size_t)bq * Mn) + (m0 + m)) * FOUTn + fo;
    size_t o1 = (((size_t)(bq + 4) * Mn) + (m0 + m)) * FOUTn + fo;
    float4* out4_0 = (float4*)&out[o0];
    float4* out4_1 = (float4*)&out[o1];
    if (accum) {
        float4 c0 = *out4_0, c1 = *out4_1;
        acc0.x += c0.x; acc0.y += c0.y; acc0.z += c0.z; acc0.w += c0.w;
        acc1.x += c1.x; acc1.y += c1.y; acc1.z += c1.z; acc1.w += c1.w;
    }
    *out4_0 = acc0;
    *out4_1 = acc1;
}

// ---------------- launch ----------------

extern "C" void kernel_launch(void* const* d_in, const int* in_sizes, int n_in,
                              void* d_out, int out_size, void* d_ws, size_t ws_size,
                              hipStream_t stream) {
    const float* x         = (const float*)d_in[0];
    const float* edge_vals = (const float*)d_in[1];
    const float* W         = (const float*)d_in[2];
    const int*   edge_rows = (const int*)d_in[3];
    const int*   edge_cols = (const int*)d_in[4];
    float* out = (float*)d_out;

    char* ws = (char*)d_ws;
    const size_t bufB = (size_t)Mn * Cn * sizeof(float);   // 81.92 MB fp32 level
    const size_t bufH = (size_t)Mn * Cn * sizeof(ushort);  // 40.96 MB fp16 level
    const size_t wfB  = 12 * 4 * 64 * 8 * sizeof(ushort);  // 48 KB
    const size_t csrB = (size_t)(Mn + 4 + Mn) * 4 + (size_t)NNZn * 8;  // ~2.9 MB

    const int spmm_grid = Mn / 4;
    const int gemm_grid = (Mn / 64) * 8;

    // primary plan: 6 fp16 level slots (248.69 MB total), layout [lev][b][m][f]
    if (ws_size >= 6 * bufH + wfB + csrB) {
        ushort* xh  = (ushort*)ws;                       // slot l at xh + l*Mn*Cn
        ushort* wfr = (ushort*)(ws + 6 * bufH);
        int*    rowptr = (int*)(ws + 6 * bufH + wfB);
        int*    fill   = rowptr + (Mn + 4);              // doubles as wcur
        int2*   csr    = (int2*)(fill + Mn);
        // scan scratch lives in the (not yet written) csr buffer
        int*    bsum   = (int*)csr;
        int*    boff   = bsum + 256;
        ushort* slot[6];
        for (int l = 0; l < 6; ++l) slot[l] = xh + (size_t)l * Mn * Cn;

        // CSR build (every call; ws re-poisoned by harness)
        hipMemsetAsync(fill, 0, Mn * sizeof(int), stream);
        k_hist<<<(NNZn + 255) / 256, 256, 0, stream>>>(edge_rows, fill);
        k_scan_part<<<NB, 256, 0, stream>>>(fill, rowptr, bsum);
        k_scan_bsums<<<1, 256, 0, stream>>>(bsum, boff, rowptr);
        k_scan_add<<<NB, 256, 0, stream>>>(rowptr, boff, fill);   // fill := wcur
        k_scatter<<<(NNZn + 255) / 256, 256, 0, stream>>>(edge_rows, edge_cols,
                                                          edge_vals, fill, csr);
        k_wfrag<<<96, 256, 0, stream>>>(W, wfr);

        // level 0 = streaming convert, then the 5 Chebyshev SpMMs
        k_transpose_h<<<(Bn * Mn * FINn) / (256 * 8), 256, 0, stream>>>(x, slot[0]);
        k_spmm_h<<<spmm_grid, 256, 0, stream>>>(slot[0], slot[0], slot[1],
                                                rowptr, csr, 1);
        k_spmm_h<<<spmm_grid, 256, 0, stream>>>(slot[1], slot[0], slot[2],
                                                rowptr, csr, 0);
        k_spmm_h<<<spmm_grid, 256, 0, stream>>>(slot[2], slot[1], slot[3],
                                                rowptr, csr, 0);
        k_spmm_h<<<spmm_grid, 256, 0, stream>>>(slot[3], slot[2], slot[4],
                                                rowptr, csr, 0);
        k_spmm_h<<<spmm_grid, 256, 0, stream>>>(slot[4], slot[3], slot[5],
                                                rowptr, csr, 0);
        // single-pass projection over all 6 levels (no out RMW)
        k_gemm_mfma<<<gemm_grid, 256, 0, stream>>>(xh, wfr, out);
    } else {
        // fp32 fallback: 3 rotating fp32 buffers + fp32 vector GEMM (old layout)
        float* buf0 = (float*)(ws);
        float* buf1 = (float*)(ws + bufB);
        float* buf2 = (float*)(ws + 2 * bufB);
        int*   rowptr = (int*)(ws + 3 * bufB);
        int*   fill   = rowptr + (Mn + 4);
        int2*  csr    = (int2*)(fill + Mn);
        int*   bsum   = (int*)csr;
        int*   boff   = bsum + 256;
        hipMemsetAsync(fill, 0, Mn * sizeof(int), stream);
        k_hist<<<(NNZn + 255) / 256, 256, 0, stream>>>(edge_rows, fill);
        k_scan_part<<<NB, 256, 0, stream>>>(fill, rowptr, bsum);
        k_scan_bsums<<<1, 256, 0, stream>>>(bsum, boff, rowptr);
        k_scan_add<<<NB, 256, 0, stream>>>(rowptr, boff, fill);
        k_scatter<<<(NNZn + 255) / 256, 256, 0, stream>>>(edge_rows, edge_cols,
                                                          edge_vals, fill, csr);
        k_transpose_f<<<Mn, 512, 0, stream>>>(x, buf0);
        k_spmm_f32<<<spmm_grid, 256, 0, stream>>>((const float4*)buf0, (const float4*)buf0,
                                                  (float4*)buf1, rowptr, csr, 1);
        k_gemm2<<<Mn / 4, 256, 0, stream>>>(buf0, buf1, W, out, 0, 1, 0);
        k_spmm_f32<<<spmm_grid, 256, 0, stream>>>((const float4*)buf1, (const float4*)buf0,
                                                  (float4*)buf2, rowptr, csr, 0);
        k_spmm_f32<<<spmm_grid, 256, 0, stream>>>((const float4*)buf2, (const float4*)buf1,
                                                  (float4*)buf0, rowptr, csr, 0);
        k_gemm2<<<Mn / 4, 256, 0, stream>>>(buf2, buf0, W, out, 2, 3, 1);
        k_spmm_f32<<<spmm_grid, 256, 0, stream>>>((const float4*)buf0, (const float4*)buf2,
                                                  (float4*)buf1, rowptr, csr, 0);
        k_spmm_f32<<<spmm_grid, 256, 0, stream>>>((const float4*)buf1, (const float4*)buf0,
                                                  (float4*)buf2, rowptr, csr, 0);
        k_gemm2<<<Mn / 4, 256, 0, stream>>>(buf1, buf2, W, out, 4, 5, 1);
    }
}

// Round 4
// 570.986 us; speedup vs baseline: 1.1122x; 1.1122x over previous
//
#include <hip/hip_runtime.h>

// Problem constants (MeshConv: B=8, M=40000, FIN=64, K=6, FOUT=64, NNZ=320000)
#define Mn    40000
#define Bn    8
#define FINn  64
#define Kn    6
#define FOUTn 64
#define NNZn  320000
#define Cn    512   // FIN*B values per Chebyshev level per row
#define NB    ((Mn + 255) / 256)   // scan blocks = 157

// Level layout (fp16): xh[lev][b][m][f]  -- f contiguous (64 halves = 128B/row).

typedef _Float16 half8 __attribute__((ext_vector_type(8)));  // MFMA A/B frag
typedef __attribute__((ext_vector_type(4))) float floatx4;   // MFMA accumulator

__device__ __forceinline__ ushort f2h(float f) {
    _Float16 h = (_Float16)f;
    return *(ushort*)&h;
}

// ---------------- CSR build ----------------

__global__ __launch_bounds__(256) void k_hist(const int* __restrict__ rows,
                                              int* __restrict__ cnt) {
    int e = blockIdx.x * 256 + threadIdx.x;
    if (e < NNZn) atomicAdd(&cnt[rows[e]], 1);
}

// hierarchical scan, phase 1: per-block local exclusive scan + block sums
__global__ __launch_bounds__(256) void k_scan_part(const int* __restrict__ cnt,
                                                   int* __restrict__ rowptr,
                                                   int* __restrict__ bsum) {
    __shared__ int part[256];
    int tid = threadIdx.x;
    int r = blockIdx.x * 256 + tid;
    int v = (r < Mn) ? cnt[r] : 0;
    part[tid] = v;
    __syncthreads();
    for (int off = 1; off < 256; off <<= 1) {
        int t = (tid >= off) ? part[tid - off] : 0;
        __syncthreads();
        part[tid] += t;
        __syncthreads();
    }
    if (r < Mn) rowptr[r] = part[tid] - v;     // block-local exclusive prefix
    if (tid == 255) bsum[blockIdx.x] = part[255];
}

// phase 2: single-block scan of the NB block sums
__global__ __launch_bounds__(256) void k_scan_bsums(const int* __restrict__ bsum,
                                                    int* __restrict__ boff,
                                                    int* __restrict__ rowptr) {
    __shared__ int part[256];
    int tid = threadIdx.x;
    int v = (tid < NB) ? bsum[tid] : 0;
    part[tid] = v;
    __syncthreads();
    for (int off = 1; off < 256; off <<= 1) {
        int t = (tid >= off) ? part[tid - off] : 0;
        __syncthreads();
        part[tid] += t;
        __syncthreads();
    }
    if (tid < NB) boff[tid] = part[tid] - v;
    if (tid == 255) rowptr[Mn] = part[255];    // grand total
}

// phase 3: add block offsets; also emit the scatter write-cursor copy
__global__ __launch_bounds__(256) void k_scan_add(int* __restrict__ rowptr,
                                                  const int* __restrict__ boff,
                                                  int* __restrict__ wcur) {
    int r = blockIdx.x * 256 + threadIdx.x;
    if (r < Mn) {
        int v = rowptr[r] + boff[blockIdx.x];
        rowptr[r] = v;
        wcur[r] = v;
    }
}

__global__ __launch_bounds__(256) void k_scatter(const int* __restrict__ rows,
                                                 const int* __restrict__ cols,
                                                 const float* __restrict__ vals,
                                                 int* __restrict__ wcur,
                                                 int2* __restrict__ csr) {
    int e = blockIdx.x * 256 + threadIdx.x;
    if (e < NNZn) {
        int p = atomicAdd(&wcur[rows[e]], 1);
        int2 cv; cv.x = cols[e]; cv.y = __float_as_int(vals[e]);
        csr[p] = cv;
    }
}

// ---------------- x -> x0 (fp16): pure streaming convert ----------------
// x is [B][M][F] fp32, level-0 slot is [b][m][f] fp16 -> identical ordering.

__global__ __launch_bounds__(256) void k_transpose_h(const float* __restrict__ x,
                                                     ushort* __restrict__ x0h) {
    size_t i = ((size_t)blockIdx.x * 256 + threadIdx.x) * 8;   // half index
    float4 a = *(const float4*)(x + i);
    float4 b = *(const float4*)(x + i + 4);
    union { uint4 u; ushort h[8]; } s;
    s.h[0] = f2h(a.x); s.h[1] = f2h(a.y); s.h[2] = f2h(a.z); s.h[3] = f2h(a.w);
    s.h[4] = f2h(b.x); s.h[5] = f2h(b.y); s.h[6] = f2h(b.z); s.h[7] = f2h(b.w);
    *(uint4*)(x0h + i) = s.u;
}

// ---------------- SpMM (all-fp16 state) + Chebyshev recurrence ----------------
// acc = -xc[m] + sum val * xc[col] (fp32 arithmetic, fp16 storage);
// xn = first ? acc : 2*acc - xp.  One row per wave: lane l covers b = l>>3,
// f = (l&7)*8 .. +8  (8 chunks of 128B at Mn*128B stride).
// Edge loop unrolled 8-deep; xp read issued BEFORE the loop (overlaps gathers).

__device__ __forceinline__ void fmah8(float* a, uint4 g, float w) {
    union { uint4 u; _Float16 h[8]; } c; c.u = g;
#pragma unroll
    for (int i = 0; i < 8; ++i) a[i] += w * (float)c.h[i];
}

__global__ __launch_bounds__(256) void k_spmm_h(const ushort* __restrict__ xc,
                                                const ushort* __restrict__ xp,
                                                ushort* __restrict__ xn,
                                                const int* __restrict__ rowptr,
                                                const int2* __restrict__ csr,
                                                int first) {
    int t = threadIdx.x;
    int lane = t & 63;
    int m = blockIdx.x * 4 + (t >> 6);
    const uint4* xc4 = (const uint4*)xc;
    // per-lane constant offset in uint4 units: b*(Mn*8) + part
    size_t loff = (size_t)(lane >> 3) * ((size_t)Mn * 8) + (lane & 7);
    uint4 v = xc4[loff + (size_t)m * 8];
    uint4 p;
    if (!first) p = ((const uint4*)xp)[loff + (size_t)m * 8];   // early issue
    float a[8];
    { union { uint4 u; _Float16 h[8]; } c; c.u = v;
#pragma unroll
      for (int i = 0; i < 8; ++i) a[i] = -(float)c.h[i]; }

    int e = rowptr[m], end = rowptr[m + 1];
    for (; e + 8 <= end; e += 8) {
        int2 cv[8];
#pragma unroll
        for (int i = 0; i < 8; ++i) cv[i] = csr[e + i];
        uint4 g[8];
#pragma unroll
        for (int i = 0; i < 8; ++i) g[i] = xc4[loff + (size_t)cv[i].x * 8];
#pragma unroll
        for (int i = 0; i < 8; ++i) fmah8(a, g[i], __int_as_float(cv[i].y));
    }
    for (; e + 4 <= end; e += 4) {
        int2 cv0 = csr[e],     cv1 = csr[e + 1];
        int2 cv2 = csr[e + 2], cv3 = csr[e + 3];
        uint4 g0 = xc4[loff + (size_t)cv0.x * 8];
        uint4 g1 = xc4[loff + (size_t)cv1.x * 8];
        uint4 g2 = xc4[loff + (size_t)cv2.x * 8];
        uint4 g3 = xc4[loff + (size_t)cv3.x * 8];
        fmah8(a, g0, __int_as_float(cv0.y));
        fmah8(a, g1, __int_as_float(cv1.y));
        fmah8(a, g2, __int_as_float(cv2.y));
        fmah8(a, g3, __int_as_float(cv3.y));
    }
    for (; e < end; ++e) {
        int2 cv = csr[e];
        uint4 g = xc4[loff + (size_t)cv.x * 8];
        fmah8(a, g, __int_as_float(cv.y));
    }

    if (!first) {
        union { uint4 u; _Float16 h[8]; } c; c.u = p;
#pragma unroll
        for (int i = 0; i < 8; ++i) a[i] = 2.f * a[i] - (float)c.h[i];
    }
    union { uint4 u; _Float16 h[8]; } s;
#pragma unroll
    for (int i = 0; i < 8; ++i) s.h[i] = (_Float16)a[i];
    ((uint4*)xn)[loff + (size_t)m * 8] = s.u;
}

// ---------------- W -> MFMA B-fragment pre-swizzle (fp16) ----------------
// Wfrag[((kk*4 + n)*64 + lane)*8 + j] = f16( W[(f*6+lev)*64 + fo] )
//   kk = global K-chunk (0..11), lev = kk>>1, f = (kk&1)*32 + (lane>>4)*8 + j,
//   fo = n*16 + (lane&15)

__global__ __launch_bounds__(256) void k_wfrag(const float* __restrict__ W,
                                               ushort* __restrict__ wfrag) {
    int idx = blockIdx.x * 256 + threadIdx.x;   // 12*4*64*8 = 24576
    if (idx >= 12 * 4 * 64 * 8) return;
    int j    = idx & 7;
    int lane = (idx >> 3) & 63;
    int n    = (idx >> 9) & 3;
    int kk   = idx >> 11;
    int k    = (lane >> 4) * 8 + j;
    int lev  = kk >> 1;
    int f    = (kk & 1) * 32 + k;
    int fo   = n * 16 + (lane & 15);
    wfrag[idx] = f2h(W[(f * Kn + lev) * FOUTn + fo]);
}

// ---------------- MFMA projection GEMM (fp16 inputs, fp32 acc) ----------------
// out[b, m, fo] = sum over all 6 levels, f:
//   X[lev][b][m][f] * W[(f*6+lev)*64+fo]
// LDS-FREE: each lane's A-fragment (8 contiguous halves at row m0+wv*16+r,
// f = half*32 + q*8) is loaded directly from global -- the [lev][b][m][f]
// layout makes that pattern coalesced (equal-r lanes with increasing q cover
// 64B dense). All 12 level-fragments are prefetched into NAMED half8 regs
// (no arrays -> no scratch; R3's va[6]/vb[6] spilled: VGPR 40 + 245MB scratch).

__global__ __launch_bounds__(256, 2) void k_gemm_mfma(const ushort* __restrict__ xh,
                                                      const ushort* __restrict__ wfrag,
                                                      float* __restrict__ out) {
    int t    = threadIdx.x;
    int wv   = t >> 6;
    int lane = t & 63;
    int q    = lane >> 4, r = lane & 15;
    int b    = blockIdx.x & 7;
    int m0   = (blockIdx.x >> 3) * 64;

    const size_t lstrideH = (size_t)Bn * Mn * 64;   // level stride in halves
    const ushort* abase = xh + ((size_t)b * Mn + m0 + wv * 16 + r) * 64 + q * 8;

    // prefetch all 12 A-fragments (named scalars -> guaranteed VGPRs)
    half8 aA0 = *(const half8*)(abase);
    half8 aB0 = *(const half8*)(abase + 32);
    half8 aA1 = *(const half8*)(abase + 1 * lstrideH);
    half8 aB1 = *(const half8*)(abase + 1 * lstrideH + 32);
    half8 aA2 = *(const half8*)(abase + 2 * lstrideH);
    half8 aB2 = *(const half8*)(abase + 2 * lstrideH + 32);
    half8 aA3 = *(const half8*)(abase + 3 * lstrideH);
    half8 aB3 = *(const half8*)(abase + 3 * lstrideH + 32);
    half8 aA4 = *(const half8*)(abase + 4 * lstrideH);
    half8 aB4 = *(const half8*)(abase + 4 * lstrideH + 32);
    half8 aA5 = *(const half8*)(abase + 5 * lstrideH);
    half8 aB5 = *(const half8*)(abase + 5 * lstrideH + 32);

    floatx4 acc[4];
    acc[0] = (floatx4)0.f; acc[1] = (floatx4)0.f;
    acc[2] = (floatx4)0.f; acc[3] = (floatx4)0.f;

#define MC_HALF(kkg, af)                                                              \
    do {                                                                              \
        const ushort* wf = wfrag + ((size_t)((kkg) * 4) * 64 + lane) * 8;             \
        acc[0] = __builtin_amdgcn_mfma_f32_16x16x32_f16(af, *(const half8*)(wf),        acc[0], 0, 0, 0); \
        acc[1] = __builtin_amdgcn_mfma_f32_16x16x32_f16(af, *(const half8*)(wf + 512),  acc[1], 0, 0, 0); \
        acc[2] = __builtin_amdgcn_mfma_f32_16x16x32_f16(af, *(const half8*)(wf + 1024), acc[2], 0, 0, 0); \
        acc[3] = __builtin_amdgcn_mfma_f32_16x16x32_f16(af, *(const half8*)(wf + 1536), acc[3], 0, 0, 0); \
    } while (0)

    MC_HALF(0,  aA0); MC_HALF(1,  aB0);
    MC_HALF(2,  aA1); MC_HALF(3,  aB1);
    MC_HALF(4,  aA2); MC_HALF(5,  aB2);
    MC_HALF(6,  aA3); MC_HALF(7,  aB3);
    MC_HALF(8,  aA4); MC_HALF(9,  aB4);
    MC_HALF(10, aA5); MC_HALF(11, aB5);
#undef MC_HALF

    // C/D layout: col = lane&15, row = (lane>>4)*4 + reg
    size_t obase = ((size_t)b * Mn + m0 + wv * 16) * FOUTn;
#pragma unroll
    for (int n = 0; n < 4; ++n) {
#pragma unroll
        for (int reg = 0; reg < 4; ++reg) {
            int orow = q * 4 + reg;
            out[obase + (size_t)orow * FOUTn + n * 16 + r] = acc[n][reg];
        }
    }
}

// ---------------- fallback fp32 kernels (ws too small; not expected) ----------------

__global__ __launch_bounds__(512) void k_transpose_f(const float* __restrict__ x,
                                                     float* __restrict__ x0) {
    int m = blockIdx.x, t = threadIdx.x;
    int b = t >> 6, f = t & 63;
    x0[(size_t)m * Cn + t] = x[((size_t)b * Mn + m) * 64 + f];
}

__global__ __launch_bounds__(256) void k_spmm_f32(const float4* __restrict__ xc,
                                                  const float4* __restrict__ xp,
                                                  float4* __restrict__ xn,
                                                  const int* __restrict__ rowptr,
                                                  const int2* __restrict__ csr,
                                                  int first) {
    int t = threadIdx.x;
    int lane = t & 63;
    int m = blockIdx.x * 4 + (t >> 6);
    size_t rb = (size_t)m * 128;
    float4 v0 = xc[rb + lane];
    float4 v1 = xc[rb + 64 + lane];
    float4 a0 = make_float4(-v0.x, -v0.y, -v0.z, -v0.w);
    float4 a1 = make_float4(-v1.x, -v1.y, -v1.z, -v1.w);
    int e = rowptr[m], end = rowptr[m + 1];
    for (; e < end; ++e) {
        int2 cv = csr[e];
        float w = __int_as_float(cv.y);
        const float4* r = xc + (size_t)cv.x * 128;
        float4 g0 = r[lane], g1 = r[64 + lane];
        a0.x += w * g0.x; a0.y += w * g0.y; a0.z += w * g0.z; a0.w += w * g0.w;
        a1.x += w * g1.x; a1.y += w * g1.y; a1.z += w * g1.z; a1.w += w * g1.w;
    }
    if (!first) {
        float4 p0 = xp[rb + lane];
        float4 p1 = xp[rb + 64 + lane];
        a0.x = 2.f * a0.x - p0.x; a0.y = 2.f * a0.y - p0.y;
        a0.z = 2.f * a0.z - p0.z; a0.w = 2.f * a0.w - p0.w;
        a1.x = 2.f * a1.x - p1.x; a1.y = 2.f * a1.y - p1.y;
        a1.z = 2.f * a1.z - p1.z; a1.w = 2.f * a1.w - p1.w;
    }
    xn[rb + lane] = a0;
    xn[rb + 64 + lane] = a1;
}

__global__ __launch_bounds__(256) void k_gemm2(const float* __restrict__ xa,
                                               const float* __restrict__ xb,
                                               const float* __restrict__ W,
                                               float* __restrict__ out,
                                               int ka, int kb, int accum) {
    __shared__ __align__(16) float Wa[64 * 64];
    __shared__ __align__(16) float Wb[64 * 64];
    __shared__ __align__(16) float xsa[4 * Cn];
    __shared__ __align__(16) float xsb[4 * Cn];
    int t = threadIdx.x;
    size_t m0 = (size_t)blockIdx.x * 4;
    for (int i = t; i < 4096; i += 256) {
        int f = i >> 6, fo = i & 63;
        Wa[i] = W[(f * Kn + ka) * FOUTn + fo];
        Wb[i] = W[(f * Kn + kb) * FOUTn + fo];
    }
    for (int i = t; i < 4 * Cn; i += 256) {
        xsa[i] = xa[m0 * Cn + i];
        xsb[i] = xb[m0 * Cn + i];
    }
    __syncthreads();
    int fo  = (t & 15) * 4;
    int idx = t >> 4;
    int m   = idx & 3;
    int bq  = idx >> 2;
    float4 acc0 = make_float4(0.f, 0.f, 0.f, 0.f);
    float4 acc1 = make_float4(0.f, 0.f, 0.f, 0.f);
    for (int f = 0; f < 64; ++f) {
        float4 wa = *(const float4*)&Wa[f * 64 + fo];
        float a0 = xsa[m * Cn + bq * 64 + f];
        float a1 = xsa[m * Cn + (bq + 4) * 64 + f];
        acc0.x += a0 * wa.x; acc0.y += a0 * wa.y; acc0.z += a0 * wa.z; acc0.w += a0 * wa.w;
        acc1.x += a1 * wa.x; acc1.y += a1 * wa.y; acc1.z += a1 * wa.z; acc1.w += a1 * wa.w;
        float4 wb = *(const float4*)&Wb[f * 64 + fo];
        float b0 = xsb[m * Cn + bq * 64 + f];
        float b1 = xsb[m * Cn + (bq + 4) * 64 + f];
        acc0.x += b0 * wb.x; acc0.y += b0 * wb.y; acc0.z += b0 * wb.z; acc0.w += b0 * wb.w;
        acc1.x += b1 * wb.x; acc1.y += b1 * wb.y; acc1.z += b1 * wb.z; acc1.w += b1 * wb.w;
    }
    size_t o0 = (((size_t)bq * Mn) + (m0 + m)) * FOUTn + fo;
    size_t o1 = (((size_t)(bq + 4) * Mn) + (m0 + m)) * FOUTn + fo;
    float4* out4_0 = (float4*)&out[o0];
    float4* out4_1 = (float4*)&out[o1];
    if (accum) {
        float4 c0 = *out4_0, c1 = *out4_1;
        acc0.x += c0.x; acc0.y += c0.y; acc0.z += c0.z; acc0.w += c0.w;
        acc1.x += c1.x; acc1.y += c1.y; acc1.z += c1.z; acc1.w += c1.w;
    }
    *out4_0 = acc0;
    *out4_1 = acc1;
}

// ---------------- launch ----------------

extern "C" void kernel_launch(void* const* d_in, const int* in_sizes, int n_in,
                              void* d_out, int out_size, void* d_ws, size_t ws_size,
                              hipStream_t stream) {
    const float* x         = (const float*)d_in[0];
    const float* edge_vals = (const float*)d_in[1];
    const float* W         = (const float*)d_in[2];
    const int*   edge_rows = (const int*)d_in[3];
    const int*   edge_cols = (const int*)d_in[4];
    float* out = (float*)d_out;

    char* ws = (char*)d_ws;
    const size_t bufB = (size_t)Mn * Cn * sizeof(float);   // 81.92 MB fp32 level
    const size_t bufH = (size_t)Mn * Cn * sizeof(ushort);  // 40.96 MB fp16 level
    const size_t wfB  = 12 * 4 * 64 * 8 * sizeof(ushort);  // 48 KB
    const size_t csrB = (size_t)(Mn + 4 + Mn) * 4 + (size_t)NNZn * 8;  // ~2.9 MB

    const int spmm_grid = Mn / 4;
    const int gemm_grid = (Mn / 64) * 8;

    // primary plan: 6 fp16 level slots (248.69 MB total), layout [lev][b][m][f]
    if (ws_size >= 6 * bufH + wfB + csrB) {
        ushort* xh  = (ushort*)ws;                       // slot l at xh + l*Mn*Cn
        ushort* wfr = (ushort*)(ws + 6 * bufH);
        int*    rowptr = (int*)(ws + 6 * bufH + wfB);
        int*    fill   = rowptr + (Mn + 4);              // doubles as wcur
        int2*   csr    = (int2*)(fill + Mn);
        // scan scratch lives in the (not yet written) csr buffer
        int*    bsum   = (int*)csr;
        int*    boff   = bsum + 256;
        ushort* slot[6];
        for (int l = 0; l < 6; ++l) slot[l] = xh + (size_t)l * Mn * Cn;

        // CSR build (every call; ws re-poisoned by harness)
        hipMemsetAsync(fill, 0, Mn * sizeof(int), stream);
        k_hist<<<(NNZn + 255) / 256, 256, 0, stream>>>(edge_rows, fill);
        k_scan_part<<<NB, 256, 0, stream>>>(fill, rowptr, bsum);
        k_scan_bsums<<<1, 256, 0, stream>>>(bsum, boff, rowptr);
        k_scan_add<<<NB, 256, 0, stream>>>(rowptr, boff, fill);   // fill := wcur
        k_scatter<<<(NNZn + 255) / 256, 256, 0, stream>>>(edge_rows, edge_cols,
                                                          edge_vals, fill, csr);
        k_wfrag<<<96, 256, 0, stream>>>(W, wfr);

        // level 0 = streaming convert, then the 5 Chebyshev SpMMs
        k_transpose_h<<<(Bn * Mn * FINn) / (256 * 8), 256, 0, stream>>>(x, slot[0]);
        k_spmm_h<<<spmm_grid, 256, 0, stream>>>(slot[0], slot[0], slot[1],
                                                rowptr, csr, 1);
        k_spmm_h<<<spmm_grid, 256, 0, stream>>>(slot[1], slot[0], slot[2],
                                                rowptr, csr, 0);
        k_spmm_h<<<spmm_grid, 256, 0, stream>>>(slot[2], slot[1], slot[3],
                                                rowptr, csr, 0);
        k_spmm_h<<<spmm_grid, 256, 0, stream>>>(slot[3], slot[2], slot[4],
                                                rowptr, csr, 0);
        k_spmm_h<<<spmm_grid, 256, 0, stream>>>(slot[4], slot[3], slot[5],
                                                rowptr, csr, 0);
        // single-pass projection over all 6 levels (no out RMW)
        k_gemm_mfma<<<gemm_grid, 256, 0, stream>>>(xh, wfr, out);
    } else {
        // fp32 fallback: 3 rotating fp32 buffers + fp32 vector GEMM (old layout)
        float* buf0 = (float*)(ws);
        float* buf1 = (float*)(ws + bufB);
        float* buf2 = (float*)(ws + 2 * bufB);
        int*   rowptr = (int*)(ws + 3 * bufB);
        int*   fill   = rowptr + (Mn + 4);
        int2*  csr    = (int2*)(fill + Mn);
        int*   bsum   = (int*)csr;
        int*   boff   = bsum + 256;
        hipMemsetAsync(fill, 0, Mn * sizeof(int), stream);
        k_hist<<<(NNZn + 255) / 256, 256, 0, stream>>>(edge_rows, fill);
        k_scan_part<<<NB, 256, 0, stream>>>(fill, rowptr, bsum);
        k_scan_bsums<<<1, 256, 0, stream>>>(bsum, boff, rowptr);
        k_scan_add<<<NB, 256, 0, stream>>>(rowptr, boff, fill);
        k_scatter<<<(NNZn + 255) / 256, 256, 0, stream>>>(edge_rows, edge_cols,
                                                          edge_vals, fill, csr);
        k_transpose_f<<<Mn, 512, 0, stream>>>(x, buf0);
        k_spmm_f32<<<spmm_grid, 256, 0, stream>>>((const float4*)buf0, (const float4*)buf0,
                                                  (float4*)buf1, rowptr, csr, 1);
        k_gemm2<<<Mn / 4, 256, 0, stream>>>(buf0, buf1, W, out, 0, 1, 0);
        k_spmm_f32<<<spmm_grid, 256, 0, stream>>>((const float4*)buf1, (const float4*)buf0,
                                                  (float4*)buf2, rowptr, csr, 0);
        k_spmm_f32<<<spmm_grid, 256, 0, stream>>>((const float4*)buf2, (const float4*)buf1,
                                                  (float4*)buf0, rowptr, csr, 0);
        k_gemm2<<<Mn / 4, 256, 0, stream>>>(buf2, buf0, W, out, 2, 3, 1);
        k_spmm_f32<<<spmm_grid, 256, 0, stream>>>((const float4*)buf0, (const float4*)buf2,
                                                  (float4*)buf1, rowptr, csr, 0);
        k_spmm_f32<<<spmm_grid, 256, 0, stream>>>((const float4*)buf1, (const float4*)buf0,
                                                  (float4*)buf2, rowptr, csr, 0);
        k_gemm2<<<Mn / 4, 256, 0, stream>>>(buf1, buf2, W, out, 4, 5, 1);
    }
}

// Round 5
// 543.819 us; speedup vs baseline: 1.1678x; 1.0500x over previous
//
#include <hip/hip_runtime.h>

// Problem constants (MeshConv: B=8, M=40000, FIN=64, K=6, FOUT=64, NNZ=320000)
#define Mn    40000
#define Bn    8
#define FINn  64
#define Kn    6
#define FOUTn 64
#define NNZn  320000
#define Cn    512   // FIN*B values per level row; OUR convention c = b*64 + f
#define NB    ((Mn + 255) / 256)   // scan blocks = 157
#define MT    (Mn / 64)            // 625 m-tiles for the GEMM

// Level layout (fp16): xh[lev][m][c], c = b*64+f  -- one row = 1KB contiguous,
// so each SpMM edge-gather is a single fully-coalesced 1KB wave transaction
// (64 lanes x 16B). The GEMM A-fragment (8 contiguous halves inside one
// b-slice) is equally coalesced in this layout.

typedef _Float16 half8 __attribute__((ext_vector_type(8)));  // MFMA A/B frag
typedef __attribute__((ext_vector_type(4))) float floatx4;   // MFMA accumulator

__device__ __forceinline__ ushort f2h(float f) {
    _Float16 h = (_Float16)f;
    return *(ushort*)&h;
}

// ---------------- CSR build ----------------

__global__ __launch_bounds__(256) void k_hist(const int* __restrict__ rows,
                                              int* __restrict__ cnt) {
    int e = blockIdx.x * 256 + threadIdx.x;
    if (e < NNZn) atomicAdd(&cnt[rows[e]], 1);
}

// hierarchical scan, phase 1: per-block local exclusive scan + block sums
__global__ __launch_bounds__(256) void k_scan_part(const int* __restrict__ cnt,
                                                   int* __restrict__ rowptr,
                                                   int* __restrict__ bsum) {
    __shared__ int part[256];
    int tid = threadIdx.x;
    int r = blockIdx.x * 256 + tid;
    int v = (r < Mn) ? cnt[r] : 0;
    part[tid] = v;
    __syncthreads();
    for (int off = 1; off < 256; off <<= 1) {
        int t = (tid >= off) ? part[tid - off] : 0;
        __syncthreads();
        part[tid] += t;
        __syncthreads();
    }
    if (r < Mn) rowptr[r] = part[tid] - v;     // block-local exclusive prefix
    if (tid == 255) bsum[blockIdx.x] = part[255];
}

// phase 2: single-block scan of the NB block sums
__global__ __launch_bounds__(256) void k_scan_bsums(const int* __restrict__ bsum,
                                                    int* __restrict__ boff,
                                                    int* __restrict__ rowptr) {
    __shared__ int part[256];
    int tid = threadIdx.x;
    int v = (tid < NB) ? bsum[tid] : 0;
    part[tid] = v;
    __syncthreads();
    for (int off = 1; off < 256; off <<= 1) {
        int t = (tid >= off) ? part[tid - off] : 0;
        __syncthreads();
        part[tid] += t;
        __syncthreads();
    }
    if (tid < NB) boff[tid] = part[tid] - v;
    if (tid == 255) rowptr[Mn] = part[255];    // grand total
}

// phase 3: add block offsets; also emit the scatter write-cursor copy
__global__ __launch_bounds__(256) void k_scan_add(int* __restrict__ rowptr,
                                                  const int* __restrict__ boff,
                                                  int* __restrict__ wcur) {
    int r = blockIdx.x * 256 + threadIdx.x;
    if (r < Mn) {
        int v = rowptr[r] + boff[blockIdx.x];
        rowptr[r] = v;
        wcur[r] = v;
    }
}

__global__ __launch_bounds__(256) void k_scatter(const int* __restrict__ rows,
                                                 const int* __restrict__ cols,
                                                 const float* __restrict__ vals,
                                                 int* __restrict__ wcur,
                                                 int2* __restrict__ csr) {
    int e = blockIdx.x * 256 + threadIdx.x;
    if (e < NNZn) {
        int p = atomicAdd(&wcur[rows[e]], 1);
        int2 cv; cv.x = cols[e]; cv.y = __float_as_int(vals[e]);
        csr[p] = cv;
    }
}

// ---------------- x -> x0 (fp16): transpose to [m][b*64+f] ----------------
// Block = 4 m-rows; thread handles 2 float4 quads. Reads contiguous within a
// b-slice; writes 8B chunks that tile each 1KB output row contiguously.

__global__ __launch_bounds__(256) void k_transpose_h(const float* __restrict__ x,
                                                     ushort* __restrict__ x0h) {
    int m0 = blockIdx.x * 4;
    int t  = threadIdx.x;
#pragma unroll
    for (int k = 0; k < 2; ++k) {
        int i   = t + k * 256;       // 0..511
        int ml  = i >> 7;            // 0..3
        int rem = i & 127;
        int b   = rem >> 4;
        int fq  = (rem & 15) * 4;
        float4 a = *(const float4*)(x + ((size_t)b * Mn + m0 + ml) * 64 + fq);
        union { uint2 u; ushort h[4]; } s;
        s.h[0] = f2h(a.x); s.h[1] = f2h(a.y); s.h[2] = f2h(a.z); s.h[3] = f2h(a.w);
        *(uint2*)(x0h + (size_t)(m0 + ml) * Cn + b * 64 + fq) = s.u;
    }
}

// ---------------- SpMM (all-fp16 state) + Chebyshev recurrence ----------------
// acc = -xc[m] + sum val * xc[col] (fp32 arithmetic, fp16 storage);
// xn = first ? acc : 2*acc - xp.  One row per wave: 64 lanes x 16B = one
// contiguous 1KB transaction per gather. 8-deep unroll; xp issued early.

__device__ __forceinline__ void fmah8(float* a, uint4 g, float w) {
    union { uint4 u; _Float16 h[8]; } c; c.u = g;
#pragma unroll
    for (int i = 0; i < 8; ++i) a[i] += w * (float)c.h[i];
}

__global__ __launch_bounds__(256) void k_spmm_h(const ushort* __restrict__ xc,
                                                const ushort* __restrict__ xp,
                                                ushort* __restrict__ xn,
                                                const int* __restrict__ rowptr,
                                                const int2* __restrict__ csr,
                                                int first) {
    int t = threadIdx.x;
    int lane = t & 63;
    int m = blockIdx.x * 4 + (t >> 6);
    const uint4* xc4 = (const uint4*)xc;      // row = 64 uint4 (512 halves)
    uint4 v = xc4[(size_t)m * 64 + lane];
    uint4 p;
    if (!first) p = ((const uint4*)xp)[(size_t)m * 64 + lane];   // early issue
    float a[8];
    { union { uint4 u; _Float16 h[8]; } c; c.u = v;
#pragma unroll
      for (int i = 0; i < 8; ++i) a[i] = -(float)c.h[i]; }

    int e = rowptr[m], end = rowptr[m + 1];
    for (; e + 8 <= end; e += 8) {
        int2 cv[8];
#pragma unroll
        for (int i = 0; i < 8; ++i) cv[i] = csr[e + i];
        uint4 g[8];
#pragma unroll
        for (int i = 0; i < 8; ++i) g[i] = xc4[(size_t)cv[i].x * 64 + lane];
#pragma unroll
        for (int i = 0; i < 8; ++i) fmah8(a, g[i], __int_as_float(cv[i].y));
    }
    for (; e + 4 <= end; e += 4) {
        int2 cv0 = csr[e],     cv1 = csr[e + 1];
        int2 cv2 = csr[e + 2], cv3 = csr[e + 3];
        uint4 g0 = xc4[(size_t)cv0.x * 64 + lane];
        uint4 g1 = xc4[(size_t)cv1.x * 64 + lane];
        uint4 g2 = xc4[(size_t)cv2.x * 64 + lane];
        uint4 g3 = xc4[(size_t)cv3.x * 64 + lane];
        fmah8(a, g0, __int_as_float(cv0.y));
        fmah8(a, g1, __int_as_float(cv1.y));
        fmah8(a, g2, __int_as_float(cv2.y));
        fmah8(a, g3, __int_as_float(cv3.y));
    }
    for (; e < end; ++e) {
        int2 cv = csr[e];
        uint4 g = xc4[(size_t)cv.x * 64 + lane];
        fmah8(a, g, __int_as_float(cv.y));
    }

    if (!first) {
        union { uint4 u; _Float16 h[8]; } c; c.u = p;
#pragma unroll
        for (int i = 0; i < 8; ++i) a[i] = 2.f * a[i] - (float)c.h[i];
    }
    union { uint4 u; _Float16 h[8]; } s;
#pragma unroll
    for (int i = 0; i < 8; ++i) s.h[i] = (_Float16)a[i];
    ((uint4*)xn)[(size_t)m * 64 + lane] = s.u;
}

// ---------------- W -> MFMA B-fragment pre-swizzle (fp16) ----------------
// Wfrag[((kk*4 + n)*64 + lane)*8 + j] = f16( W[(f*6+lev)*64 + fo] )
//   kk = global K-chunk (0..11), lev = kk>>1, f = (kk&1)*32 + (lane>>4)*8 + j,
//   fo = n*16 + (lane&15)

__global__ __launch_bounds__(256) void k_wfrag(const float* __restrict__ W,
                                               ushort* __restrict__ wfrag) {
    int idx = blockIdx.x * 256 + threadIdx.x;   // 12*4*64*8 = 24576
    if (idx >= 12 * 4 * 64 * 8) return;
    int j    = idx & 7;
    int lane = (idx >> 3) & 63;
    int n    = (idx >> 9) & 3;
    int kk   = idx >> 11;
    int k    = (lane >> 4) * 8 + j;
    int lev  = kk >> 1;
    int f    = (kk & 1) * 32 + k;
    int fo   = n * 16 + (lane & 15);
    wfrag[idx] = f2h(W[(f * Kn + lev) * FOUTn + fo]);
}

// ---------------- MFMA projection GEMM (fp16 inputs, fp32 acc) ----------------
// out[b, m, fo] = sum over all 6 levels, f:
//   X[lev][m][b*64+f] * W[(f*6+lev)*64+fo]
// LDS-free: each lane's A-fragment is 8 contiguous halves inside one b-slice.
// All 12 level-fragments are loaded into NAMED half8 regs, then a
// sched_barrier(0) PINS them above the MFMA ladder (R4's version let the
// scheduler sink each load next to its use: VGPR=32, serial latency chain).
// Block order: b-major (b = id/MT) so concurrent blocks stream contiguously.

__global__ __launch_bounds__(256, 2) void k_gemm_mfma(const ushort* __restrict__ xh,
                                                      const ushort* __restrict__ wfrag,
                                                      float* __restrict__ out) {
    int t     = threadIdx.x;
    int wv    = t >> 6;
    int lane  = t & 63;
    int q     = lane >> 4, r = lane & 15;
    int mtile = blockIdx.x % MT;
    int b     = blockIdx.x / MT;
    int m0    = mtile * 64;

    const size_t lstrideH = (size_t)Mn * Cn;   // level stride in halves
    const ushort* abase = xh + (size_t)(m0 + wv * 16 + r) * Cn + b * 64 + q * 8;

    // issue all 12 A-fragment loads back-to-back (named -> VGPRs)
    half8 aA0 = *(const half8*)(abase);
    half8 aB0 = *(const half8*)(abase + 32);
    half8 aA1 = *(const half8*)(abase + 1 * lstrideH);
    half8 aB1 = *(const half8*)(abase + 1 * lstrideH + 32);
    half8 aA2 = *(const half8*)(abase + 2 * lstrideH);
    half8 aB2 = *(const half8*)(abase + 2 * lstrideH + 32);
    half8 aA3 = *(const half8*)(abase + 3 * lstrideH);
    half8 aB3 = *(const half8*)(abase + 3 * lstrideH + 32);
    half8 aA4 = *(const half8*)(abase + 4 * lstrideH);
    half8 aB4 = *(const half8*)(abase + 4 * lstrideH + 32);
    half8 aA5 = *(const half8*)(abase + 5 * lstrideH);
    half8 aB5 = *(const half8*)(abase + 5 * lstrideH + 32);
    __builtin_amdgcn_sched_barrier(0);   // nothing moves above; all 12 in flight

    floatx4 acc[4];
    acc[0] = (floatx4)0.f; acc[1] = (floatx4)0.f;
    acc[2] = (floatx4)0.f; acc[3] = (floatx4)0.f;

#define MC_HALF(kkg, af)                                                              \
    do {                                                                              \
        const ushort* wf = wfrag + ((size_t)((kkg) * 4) * 64 + lane) * 8;             \
        acc[0] = __builtin_amdgcn_mfma_f32_16x16x32_f16(af, *(const half8*)(wf),        acc[0], 0, 0, 0); \
        acc[1] = __builtin_amdgcn_mfma_f32_16x16x32_f16(af, *(const half8*)(wf + 512),  acc[1], 0, 0, 0); \
        acc[2] = __builtin_amdgcn_mfma_f32_16x16x32_f16(af, *(const half8*)(wf + 1024), acc[2], 0, 0, 0); \
        acc[3] = __builtin_amdgcn_mfma_f32_16x16x32_f16(af, *(const half8*)(wf + 1536), acc[3], 0, 0, 0); \
    } while (0)

    MC_HALF(0,  aA0); MC_HALF(1,  aB0);
    MC_HALF(2,  aA1); MC_HALF(3,  aB1);
    MC_HALF(4,  aA2); MC_HALF(5,  aB2);
    MC_HALF(6,  aA3); MC_HALF(7,  aB3);
    MC_HALF(8,  aA4); MC_HALF(9,  aB4);
    MC_HALF(10, aA5); MC_HALF(11, aB5);
#undef MC_HALF

    // C/D layout: col = lane&15, row = (lane>>4)*4 + reg
    size_t obase = ((size_t)b * Mn + m0 + wv * 16) * FOUTn;
#pragma unroll
    for (int n = 0; n < 4; ++n) {
#pragma unroll
        for (int reg = 0; reg < 4; ++reg) {
            int orow = q * 4 + reg;
            out[obase + (size_t)orow * FOUTn + n * 16 + r] = acc[n][reg];
        }
    }
}

// ---------------- fallback fp32 kernels (ws too small; not expected) ----------------

__global__ __launch_bounds__(512) void k_transpose_f(const float* __restrict__ x,
                                                     float* __restrict__ x0) {
    int m = blockIdx.x, t = threadIdx.x;
    int b = t >> 6, f = t & 63;
    x0[(size_t)m * Cn + t] = x[((size_t)b * Mn + m) * 64 + f];
}

__global__ __launch_bounds__(256) void k_spmm_f32(const float4* __restrict__ xc,
                                                  const float4* __restrict__ xp,
                                                  float4* __restrict__ xn,
                                                  const int* __restrict__ rowptr,
                                                  const int2* __restrict__ csr,
                                                  int first) {
    int t = threadIdx.x;
    int lane = t & 63;
    int m = blockIdx.x * 4 + (t >> 6);
    size_t rb = (size_t)m * 128;
    float4 v0 = xc[rb + lane];
    float4 v1 = xc[rb + 64 + lane];
    float4 a0 = make_float4(-v0.x, -v0.y, -v0.z, -v0.w);
    float4 a1 = make_float4(-v1.x, -v1.y, -v1.z, -v1.w);
    int e = rowptr[m], end = rowptr[m + 1];
    for (; e < end; ++e) {
        int2 cv = csr[e];
        float w = __int_as_float(cv.y);
        const float4* r = xc + (size_t)cv.x * 128;
        float4 g0 = r[lane], g1 = r[64 + lane];
        a0.x += w * g0.x; a0.y += w * g0.y; a0.z += w * g0.z; a0.w += w * g0.w;
        a1.x += w * g1.x; a1.y += w * g1.y; a1.z += w * g1.z; a1.w += w * g1.w;
    }
    if (!first) {
        float4 p0 = xp[rb + lane];
        float4 p1 = xp[rb + 64 + lane];
        a0.x = 2.f * a0.x - p0.x; a0.y = 2.f * a0.y - p0.y;
        a0.z = 2.f * a0.z - p0.z; a0.w = 2.f * a0.w - p0.w;
        a1.x = 2.f * a1.x - p1.x; a1.y = 2.f * a1.y - p1.y;
        a1.z = 2.f * a1.z - p1.z; a1.w = 2.f * a1.w - p1.w;
    }
    xn[rb + lane] = a0;
    xn[rb + 64 + lane] = a1;
}

__global__ __launch_bounds__(256) void k_gemm2(const float* __restrict__ xa,
                                               const float* __restrict__ xb,
                                               const float* __restrict__ W,
                                               float* __restrict__ out,
                                               int ka, int kb, int accum) {
    __shared__ __align__(16) float Wa[64 * 64];
    __shared__ __align__(16) float Wb[64 * 64];
    __shared__ __align__(16) float xsa[4 * Cn];
    __shared__ __align__(16) float xsb[4 * Cn];
    int t = threadIdx.x;
    size_t m0 = (size_t)blockIdx.x * 4;
    for (int i = t; i < 4096; i += 256) {
        int f = i >> 6, fo = i & 63;
        Wa[i] = W[(f * Kn + ka) * FOUTn + fo];
        Wb[i] = W[(f * Kn + kb) * FOUTn + fo];
    }
    for (int i = t; i < 4 * Cn; i += 256) {
        xsa[i] = xa[m0 * Cn + i];
        xsb[i] = xb[m0 * Cn + i];
    }
    __syncthreads();
    int fo  = (t & 15) * 4;
    int idx = t >> 4;
    int m   = idx & 3;
    int bq  = idx >> 2;
    float4 acc0 = make_float4(0.f, 0.f, 0.f, 0.f);
    float4 acc1 = make_float4(0.f, 0.f, 0.f, 0.f);
    for (int f = 0; f < 64; ++f) {
        float4 wa = *(const float4*)&Wa[f * 64 + fo];
        float a0 = xsa[m * Cn + bq * 64 + f];
        float a1 = xsa[m * Cn + (bq + 4) * 64 + f];
        acc0.x += a0 * wa.x; acc0.y += a0 * wa.y; acc0.z += a0 * wa.z; acc0.w += a0 * wa.w;
        acc1.x += a1 * wa.x; acc1.y += a1 * wa.y; acc1.z += a1 * wa.z; acc1.w += a1 * wa.w;
        float4 wb = *(const float4*)&Wb[f * 64 + fo];
        float b0 = xsb[m * Cn + bq * 64 + f];
        float b1 = xsb[m * Cn + (bq + 4) * 64 + f];
        acc0.x += b0 * wb.x; acc0.y += b0 * wb.y; acc0.z += b0 * wb.z; acc0.w += b0 * wb.w;
        acc1.x += b1 * wb.x; acc1.y += b1 * wb.y; acc1.z += b1 * wb.z; acc1.w += b1 * wb.w;
    }
    size_t o0 = (((size_t)bq * Mn) + (m0 + m)) * FOUTn + fo;
    size_t o1 = (((size_t)(bq + 4) * Mn) + (m0 + m)) * FOUTn + fo;
    float4* out4_0 = (float4*)&out[o0];
    float4* out4_1 = (float4*)&out[o1];
    if (accum) {
        float4 c0 = *out4_0, c1 = *out4_1;
        acc0.x += c0.x; acc0.y += c0.y; acc0.z += c0.z; acc0.w += c0.w;
        acc1.x += c1.x; acc1.y += c1.y; acc1.z += c1.z; acc1.w += c1.w;
    }
    *out4_0 = acc0;
    *out4_1 = acc1;
}

// ---------------- launch ----------------

extern "C" void kernel_launch(void* const* d_in, const int* in_sizes, int n_in,
                              void* d_out, int out_size, void* d_ws, size_t ws_size,
                              hipStream_t stream) {
    const float* x         = (const float*)d_in[0];
    const float* edge_vals = (const float*)d_in[1];
    const float* W         = (const float*)d_in[2];
    const int*   edge_rows = (const int*)d_in[3];
    const int*   edge_cols = (const int*)d_in[4];
    float* out = (float*)d_out;

    char* ws = (char*)d_ws;
    const size_t bufB = (size_t)Mn * Cn * sizeof(float);   // 81.92 MB fp32 level
    const size_t bufH = (size_t)Mn * Cn * sizeof(ushort);  // 40.96 MB fp16 level
    const size_t wfB  = 12 * 4 * 64 * 8 * sizeof(ushort);  // 48 KB
    const size_t csrB = (size_t)(Mn + 4 + Mn) * 4 + (size_t)NNZn * 8;  // ~2.9 MB

    const int spmm_grid = Mn / 4;
    const int gemm_grid = MT * 8;   // 5000

    // primary plan: 6 fp16 level slots (248.69 MB total), layout [lev][m][c]
    if (ws_size >= 6 * bufH + wfB + csrB) {
        ushort* xh  = (ushort*)ws;                       // slot l at xh + l*Mn*Cn
        ushort* wfr = (ushort*)(ws + 6 * bufH);
        int*    rowptr = (int*)(ws + 6 * bufH + wfB);
        int*    fill   = rowptr + (Mn + 4);              // doubles as wcur
        int2*   csr    = (int2*)(fill + Mn);
        // scan scratch lives in the (not yet written) csr buffer
        int*    bsum   = (int*)csr;
        int*    boff   = bsum + 256;
        ushort* slot[6];
        for (int l = 0; l < 6; ++l) slot[l] = xh + (size_t)l * Mn * Cn;

        // CSR build (every call; ws re-poisoned by harness)
        hipMemsetAsync(fill, 0, Mn * sizeof(int), stream);
        k_hist<<<(NNZn + 255) / 256, 256, 0, stream>>>(edge_rows, fill);
        k_scan_part<<<NB, 256, 0, stream>>>(fill, rowptr, bsum);
        k_scan_bsums<<<1, 256, 0, stream>>>(bsum, boff, rowptr);
        k_scan_add<<<NB, 256, 0, stream>>>(rowptr, boff, fill);   // fill := wcur
        k_scatter<<<(NNZn + 255) / 256, 256, 0, stream>>>(edge_rows, edge_cols,
                                                          edge_vals, fill, csr);
        k_wfrag<<<96, 256, 0, stream>>>(W, wfr);

        // transpose into level 0, then the 5 Chebyshev SpMMs
        k_transpose_h<<<Mn / 4, 256, 0, stream>>>(x, slot[0]);
        k_spmm_h<<<spmm_grid, 256, 0, stream>>>(slot[0], slot[0], slot[1],
                                                rowptr, csr, 1);
        k_spmm_h<<<spmm_grid, 256, 0, stream>>>(slot[1], slot[0], slot[2],
                                                rowptr, csr, 0);
        k_spmm_h<<<spmm_grid, 256, 0, stream>>>(slot[2], slot[1], slot[3],
                                                rowptr, csr, 0);
        k_spmm_h<<<spmm_grid, 256, 0, stream>>>(slot[3], slot[2], slot[4],
                                                rowptr, csr, 0);
        k_spmm_h<<<spmm_grid, 256, 0, stream>>>(slot[4], slot[3], slot[5],
                                                rowptr, csr, 0);
        // single-pass projection over all 6 levels (no out RMW)
        k_gemm_mfma<<<gemm_grid, 256, 0, stream>>>(xh, wfr, out);
    } else {
        // fp32 fallback: 3 rotating fp32 buffers + fp32 vector GEMM (same layout)
        float* buf0 = (float*)(ws);
        float* buf1 = (float*)(ws + bufB);
        float* buf2 = (float*)(ws + 2 * bufB);
        int*   rowptr = (int*)(ws + 3 * bufB);
        int*   fill   = rowptr + (Mn + 4);
        int2*  csr    = (int2*)(fill + Mn);
        int*   bsum   = (int*)csr;
        int*   boff   = bsum + 256;
        hipMemsetAsync(fill, 0, Mn * sizeof(int), stream);
        k_hist<<<(NNZn + 255) / 256, 256, 0, stream>>>(edge_rows, fill);
        k_scan_part<<<NB, 256, 0, stream>>>(fill, rowptr, bsum);
        k_scan_bsums<<<1, 256, 0, stream>>>(bsum, boff, rowptr);
        k_scan_add<<<NB, 256, 0, stream>>>(rowptr, boff, fill);
        k_scatter<<<(NNZn + 255) / 256, 256, 0, stream>>>(edge_rows, edge_cols,
                                                          edge_vals, fill, csr);
        k_transpose_f<<<Mn, 512, 0, stream>>>(x, buf0);
        k_spmm_f32<<<spmm_grid, 256, 0, stream>>>((const float4*)buf0, (const float4*)buf0,
                                                  (float4*)buf1, rowptr, csr, 1);
        k_gemm2<<<Mn / 4, 256, 0, stream>>>(buf0, buf1, W, out, 0, 1, 0);
        k_spmm_f32<<<spmm_grid, 256, 0, stream>>>((const float4*)buf1, (const float4*)buf0,
                                                  (float4*)buf2, rowptr, csr, 0);
        k_spmm_f32<<<spmm_grid, 256, 0, stream>>>((const float4*)buf2, (const float4*)buf1,
                                                  (float4*)buf0, rowptr, csr, 0);
        k_gemm2<<<Mn / 4, 256, 0, stream>>>(buf2, buf0, W, out, 2, 3, 1);
        k_spmm_f32<<<spmm_grid, 256, 0, stream>>>((const float4*)buf0, (const float4*)buf2,
                                                  (float4*)buf1, rowptr, csr, 0);
        k_spmm_f32<<<spmm_grid, 256, 0, stream>>>((const float4*)buf1, (const float4*)buf0,
                                                  (float4*)buf2, rowptr, csr, 0);
        k_gemm2<<<Mn / 4, 256, 0, stream>>>(buf1, buf2, W, out, 4, 5, 1);
    }
}